// Round 9
// baseline (9009.219 us; speedup 1.0000x reference)
//
#include <hip/hip_runtime.h>
#include <hip/hip_bf16.h>

#define NNODES 100000
#define NRELS  16
#define NEDGES 1600000
#define NBLKS  782               // ceil(NNODES/128)
#define NKEYS  (NBLKS * 16)      // 12512
#define GRID_MFMA 512            // persistent blocks (2/CU, LDS-capped)

typedef unsigned short u16;
typedef unsigned int   u32;
typedef __attribute__((ext_vector_type(8))) short short8;   // 8 bf16 (4 VGPRs)
typedef __attribute__((ext_vector_type(4))) float f32x4;

// ---------------- ws layout (bytes) ----------------
#define WS_INVCNT   0            // N*16 f32
#define WS_OFFS     6400000      // NKEYS+1 int
#define WS_CUR      6450064      // NKEYS int
#define WS_EMETA    6500112      // E int2 {src|(tgt&127)<<20, scale_bits}
#define WS_WTHI     19300112     // 17*128*128 bf16  [rel][col][k]
#define WS_WTLO     19857168
#define WS_CTR      20414224     // 4 job counters
#define WS_END      20414240

#define MFMA16(a, b, c) __builtin_amdgcn_mfma_f32_16x16x32_bf16((a), (b), (c), 0, 0, 0)

__device__ __forceinline__ u16 bf16_rne(float v) {
    u32 u = __float_as_uint(v);
    u32 r = (u + 0x7FFFu + ((u >> 16) & 1u)) >> 16;
    return (u16)r;
}

// ---------------- preprocessing (unchanged, R8-verified) ----------------
__global__ void hist_kernel(const int* __restrict__ tgt, const int* __restrict__ et,
                            float* __restrict__ cnt, int* __restrict__ keyCnt) {
    int e = blockIdx.x * 256 + threadIdx.x;
    if (e >= NEDGES) return;
    int t = tgt[e], r = et[e];
    atomicAdd(&cnt[t * 16 + r], 1.0f);
    atomicAdd(&keyCnt[(t >> 7) * 16 + r], 1);
}

__global__ void scan_kernel(int* __restrict__ cur, int* __restrict__ offs) {
    __shared__ int part[256];
    int t = threadIdx.x;
    int lo = t * 49, hi = min(lo + 49, NKEYS);
    int s = 0;
    for (int i = lo; i < hi; ++i) s += cur[i];
    part[t] = s;
    __syncthreads();
    if (t == 0) {
        int run = 0;
        for (int i = 0; i < 256; ++i) { int v = part[i]; part[i] = run; run += v; }
        offs[NKEYS] = run;
    }
    __syncthreads();
    int run = part[t];
    for (int i = lo; i < hi; ++i) {
        int c = cur[i];
        offs[i] = run; cur[i] = run; run += c;
    }
}

__global__ void invcnt_kernel(float* __restrict__ cnt) {
    int i = blockIdx.x * 256 + threadIdx.x;
    if (i < NNODES * 16) cnt[i] = 1.0f / fmaxf(cnt[i], 1.0f);
}

__global__ void scatter_edges(const int* __restrict__ src, const int* __restrict__ tgt,
                              const int* __restrict__ et, const float* __restrict__ invcnt,
                              int* __restrict__ cur, int2* __restrict__ eMeta) {
    int e = blockIdx.x * 256 + threadIdx.x;
    if (e >= NEDGES) return;
    int t = tgt[e], r = et[e];
    int key = (t >> 7) * 16 + r;
    int pos = atomicAdd(&cur[key], 1);
    int2 m;
    m.x = src[e] | ((t & 127) << 20);
    m.y = __float_as_int(invcnt[t * 16 + r]);
    eMeta[pos] = m;
}

// Wt[rel][col][k]: rel<16 = sum_b comp[r][b]*basis[b][k][col]; rel 16 = root[k][col]
__global__ void wprep_kernel(const float* __restrict__ comp, const float* __restrict__ basis,
                             const float* __restrict__ root,
                             u16* __restrict__ Wthi, u16* __restrict__ Wtlo) {
    int t = blockIdx.x * 256 + threadIdx.x;   // 17*128*32 = 69632
    if (t >= 17 * 128 * 32) return;
    int k4 = (t & 31) * 4, col = (t >> 5) & 127, rel = t >> 12;
    float v[4];
    if (rel < 16) {
        v[0] = v[1] = v[2] = v[3] = 0.f;
        #pragma unroll
        for (int b = 0; b < 12; ++b) {
            float c = comp[rel * 12 + b];
            #pragma unroll
            for (int kk = 0; kk < 4; ++kk)
                v[kk] += c * basis[b * 16384 + (k4 + kk) * 128 + col];
        }
    } else {
        #pragma unroll
        for (int kk = 0; kk < 4; ++kk) v[kk] = root[(k4 + kk) * 128 + col];
    }
    ushort4 h, l;
    u16* hp = (u16*)&h; u16* lp = (u16*)&l;
    #pragma unroll
    for (int kk = 0; kk < 4; ++kk) {
        hp[kk] = bf16_rne(v[kk]);
        lp[kk] = bf16_rne(v[kk] - __uint_as_float((u32)hp[kk] << 16));
    }
    size_t o = (size_t)rel * 16384 + col * 128 + k4;
    *reinterpret_cast<ushort4*>(Wthi + o) = h;
    *reinterpret_cast<ushort4*>(Wtlo + o) = l;
}

// ---------------- MFMA fused layer (named-var 3-stage pipeline) ----------------
// Persistent blocks grab 128-target jobs. Wave w = (k-half kh = w>>1, col-half
// ch = w&1): loads only its 64-k half of the 16 A rows (2x less gather than
// col-split), computes partial sums for its 64 cols, merges k-halves via the
// LDS-atomic scatter. 16-edge tiles; 3-stage rotating software pipeline with
// NAMED registers (no address-taken arrays): meta 2 tiles ahead, x-data 1 tile
// ahead, compute current. 3-term split-bf16 MFMA (rel err ~2^-16).
__global__ __launch_bounds__(256, 2) void layer_mfma(
    const float* __restrict__ xp, int xstride,
    const u16* __restrict__ Wthi, const u16* __restrict__ Wtlo,
    const float* __restrict__ bias,
    const int2* __restrict__ eMeta, const int* __restrict__ offs,
    int* __restrict__ jobCtr,
    float* __restrict__ out, int colOff)
{
    __shared__ float accS[128 * 132];   // 67,584 B -> 2 blocks/CU
    __shared__ int sJb;
    const int tid = threadIdx.x;
    const int w   = tid >> 6;
    const int kh  = w >> 1;             // k-half 0/1 (64 k each)
    const int ch  = w & 1;              // col-half 0/1 (64 cols each)
    const int l   = tid & 63;
    const int g   = l >> 4;             // k-octet / D-row group
    const int ln  = l & 15;             // A row in tile / D col in col-frag
    const int cbase = ch * 64 + ln;     // accS column index base
    const int kfl   = kh * 64 + g * 8;  // my k-octet's float offset (kc=0)

    short8 Bh[8], Bl[8];                // [cf*2+kc], constant-indexed only

#define LOADM(T, SRC, T0, T1, T2, T3, S0, S1_, S2, S3) do {                     \
        if (rel < 16) {                                                         \
            SRC = eMeta[min((T) + ln, s1 - 1)].x & 0xFFFFF;                     \
            int2 m0_ = eMeta[min((T) + 4 * g + 0, s1 - 1)];                     \
            int2 m1_ = eMeta[min((T) + 4 * g + 1, s1 - 1)];                     \
            int2 m2_ = eMeta[min((T) + 4 * g + 2, s1 - 1)];                     \
            int2 m3_ = eMeta[min((T) + 4 * g + 3, s1 - 1)];                     \
            T0 = (m0_.x >> 20) & 127; S0  = ((T)+4*g+0 < s1) ? __int_as_float(m0_.y) : 0.f; \
            T1 = (m1_.x >> 20) & 127; S1_ = ((T)+4*g+1 < s1) ? __int_as_float(m1_.y) : 0.f; \
            T2 = (m2_.x >> 20) & 127; S2  = ((T)+4*g+2 < s1) ? __int_as_float(m2_.y) : 0.f; \
            T3 = (m3_.x >> 20) & 127; S3  = ((T)+4*g+3 < s1) ? __int_as_float(m3_.y) : 0.f; \
        } else {                                                                \
            SRC = node0 + min((T) + ln, s1 - 1);                                \
            T0 = min((T)+4*g+0, s1-1); S0  = ((T)+4*g+0 < s1) ? 1.f : 0.f;      \
            T1 = min((T)+4*g+1, s1-1); S1_ = ((T)+4*g+1 < s1) ? 1.f : 0.f;      \
            T2 = min((T)+4*g+2, s1-1); S2  = ((T)+4*g+2 < s1) ? 1.f : 0.f;      \
            T3 = min((T)+4*g+3, s1-1); S3  = ((T)+4*g+3 < s1) ? 1.f : 0.f;      \
        } } while (0)

#define LOADX(SRC, X0, X1, X2, X3) do {                                         \
        const float* pa_ = xp + (size_t)(SRC) * xstride + kfl;                  \
        X0 = *reinterpret_cast<const float4*>(pa_);                             \
        X1 = *reinterpret_cast<const float4*>(pa_ + 4);                         \
        X2 = *reinterpret_cast<const float4*>(pa_ + 32);                        \
        X3 = *reinterpret_cast<const float4*>(pa_ + 36); } while (0)

#define SPLIT8(F0, F1, AH, AL) do {                                             \
        float ft_[8] = {F0.x, F0.y, F0.z, F0.w, F1.x, F1.y, F1.z, F1.w};        \
        _Pragma("unroll")                                                       \
        for (int jj = 0; jj < 8; ++jj) {                                        \
            u32 u_ = __float_as_uint(ft_[jj]);                                  \
            u16 h_ = (u16)(u_ >> 16);                                           \
            float d_ = ft_[jj] - __uint_as_float((u32)h_ << 16);                \
            AH[jj] = (short)h_; AL[jj] = (short)bf16_rne(d_);                   \
        } } while (0)

#define COMPUTE(X0, X1, X2, X3, T0, T1, T2, T3, S0, S1_, S2, S3) do {           \
        short8 ah0_, al0_, ah1_, al1_;                                          \
        SPLIT8(X0, X1, ah0_, al0_);                                             \
        SPLIT8(X2, X3, ah1_, al1_);                                             \
        _Pragma("unroll")                                                       \
        for (int cf = 0; cf < 4; ++cf) {                                        \
            f32x4 a_ = {0.f, 0.f, 0.f, 0.f};                                    \
            a_ = MFMA16(al0_, Bh[cf * 2 + 0], a_);                              \
            a_ = MFMA16(ah0_, Bl[cf * 2 + 0], a_);                              \
            a_ = MFMA16(ah0_, Bh[cf * 2 + 0], a_);                              \
            a_ = MFMA16(al1_, Bh[cf * 2 + 1], a_);                              \
            a_ = MFMA16(ah1_, Bl[cf * 2 + 1], a_);                              \
            a_ = MFMA16(ah1_, Bh[cf * 2 + 1], a_);                              \
            float* pc_ = &accS[cbase + cf * 16];                                \
            if (S0  != 0.f) atomicAdd(pc_ + T0 * 132, a_[0] * S0);              \
            if (S1_ != 0.f) atomicAdd(pc_ + T1 * 132, a_[1] * S1_);             \
            if (S2  != 0.f) atomicAdd(pc_ + T2 * 132, a_[2] * S2);              \
            if (S3  != 0.f) atomicAdd(pc_ + T3 * 132, a_[3] * S3);              \
        } } while (0)

    while (true) {
        if (tid == 0) sJb = atomicAdd(jobCtr, 1);
        __syncthreads();
        const int b = sJb;
        if (b >= NBLKS) break;
        const int node0 = b * 128;
        const int nIn = min(128, NNODES - node0);

        for (int i = tid; i < 128 * 128; i += 256)
            accS[(i >> 7) * 132 + (i & 127)] = bias[i & 127];
        __syncthreads();

        for (int rel = 0; rel <= 16; ++rel) {
            int s0, s1;
            if (rel < 16) { s0 = offs[b * 16 + rel]; s1 = offs[b * 16 + rel + 1]; }
            else          { s0 = 0; s1 = nIn; }
            if (s0 >= s1) continue;

            {   // B fragments: my col-half x my k-half, hi/lo (16 x 16B loads)
                const u16* pbh = Wthi + (size_t)rel * 16384 + (size_t)(ch * 64 + ln) * 128 + kh * 64 + g * 8;
                const u16* pbl = Wtlo + (size_t)rel * 16384 + (size_t)(ch * 64 + ln) * 128 + kh * 64 + g * 8;
                #pragma unroll
                for (int cf = 0; cf < 4; ++cf)
                    #pragma unroll
                    for (int kc = 0; kc < 2; ++kc) {
                        Bh[cf * 2 + kc] = *reinterpret_cast<const short8*>(pbh + cf * 2048 + kc * 32);
                        Bl[cf * 2 + kc] = *reinterpret_cast<const short8*>(pbl + cf * 2048 + kc * 32);
                    }
            }

            // 3-set rotating pipeline, all state in NAMED registers
            int   srcA, tA0, tA1, tA2, tA3;  float sA0, sA1, sA2, sA3;
            int   srcB, tB0, tB1, tB2, tB3;  float sB0, sB1, sB2, sB3;
            int   srcC, tC0, tC1, tC2, tC3;  float sC0, sC1, sC2, sC3;
            float4 xA0, xA1, xA2, xA3, xB0, xB1, xB2, xB3, xC0, xC1, xC2, xC3;

            int t = s0;
            LOADM(t, srcA, tA0, tA1, tA2, tA3, sA0, sA1, sA2, sA3);
            LOADX(srcA, xA0, xA1, xA2, xA3);                      // prologue stall ok
            LOADM(t + 16, srcB, tB0, tB1, tB2, tB3, sB0, sB1, sB2, sB3);
            for (;;) {
                if (t + 16 < s1) LOADX(srcB, xB0, xB1, xB2, xB3);
                LOADM(t + 32, srcC, tC0, tC1, tC2, tC3, sC0, sC1, sC2, sC3);
                COMPUTE(xA0, xA1, xA2, xA3, tA0, tA1, tA2, tA3, sA0, sA1, sA2, sA3);
                t += 16; if (t >= s1) break;

                if (t + 16 < s1) LOADX(srcC, xC0, xC1, xC2, xC3);
                LOADM(t + 32, srcA, tA0, tA1, tA2, tA3, sA0, sA1, sA2, sA3);
                COMPUTE(xB0, xB1, xB2, xB3, tB0, tB1, tB2, tB3, sB0, sB1, sB2, sB3);
                t += 16; if (t >= s1) break;

                if (t + 16 < s1) LOADX(srcA, xA0, xA1, xA2, xA3);
                LOADM(t + 32, srcB, tB0, tB1, tB2, tB3, sB0, sB1, sB2, sB3);
                COMPUTE(xC0, xC1, xC2, xC3, tC0, tC1, tC2, tC3, sC0, sC1, sC2, sC3);
                t += 16; if (t >= s1) break;
            }
        }
        __syncthreads();
        // fused ReLU + f32 store into concat slot
        for (int q = tid; q < nIn * 32; q += 256) {
            int r = q >> 5, c = (q & 31) * 4;
            float4 v = *reinterpret_cast<const float4*>(&accS[r * 132 + c]);
            v.x = fmaxf(v.x, 0.f); v.y = fmaxf(v.y, 0.f);
            v.z = fmaxf(v.z, 0.f); v.w = fmaxf(v.w, 0.f);
            *reinterpret_cast<float4*>(out + (size_t)(node0 + r) * 512 + colOff + c) = v;
        }
        __syncthreads();   // accS reuse safety before next job's init
    }
#undef LOADM
#undef LOADX
#undef SPLIT8
#undef COMPUTE
}

__global__ void emb_copy(const float* __restrict__ emb, float* __restrict__ out) {
    int q = blockIdx.x * 256 + threadIdx.x;
    int n = q >> 5, c = (q & 31) * 4;
    float4 v = *reinterpret_cast<const float4*>(emb + (size_t)n * 128 + c);
    *reinterpret_cast<float4*>(out + (size_t)n * 512 + 384 + c) = v;
}

extern "C" void kernel_launch(void* const* d_in, const int* in_sizes, int n_in,
                              void* d_out, int out_size, void* d_ws, size_t ws_size,
                              hipStream_t stream) {
    const float* emb = (const float*)d_in[0];
    const float* comp[3]  = {(const float*)d_in[1], (const float*)d_in[5], (const float*)d_in[9]};
    const float* basis[3] = {(const float*)d_in[2], (const float*)d_in[6], (const float*)d_in[10]};
    const float* root[3]  = {(const float*)d_in[3], (const float*)d_in[7], (const float*)d_in[11]};
    const float* bias[3]  = {(const float*)d_in[4], (const float*)d_in[8], (const float*)d_in[12]};
    const int* src = (const int*)d_in[13];
    const int* tgt = (const int*)d_in[14];
    const int* et  = (const int*)d_in[15];
    float* out = (float*)d_out;

    char* ws = (char*)d_ws;
    float* invcnt = (float*)(ws + WS_INVCNT);
    int*   offs   = (int*)(ws + WS_OFFS);
    int*   cur    = (int*)(ws + WS_CUR);
    int2*  eMeta  = (int2*)(ws + WS_EMETA);
    u16*   Wthi   = (u16*)(ws + WS_WTHI);
    u16*   Wtlo   = (u16*)(ws + WS_WTLO);
    int*   jobCtr = (int*)(ws + WS_CTR);
    if (ws_size < (size_t)WS_END) return;

    hipMemsetAsync(invcnt, 0, 6400000, stream);
    hipMemsetAsync(cur, 0, NKEYS * 4, stream);
    hipMemsetAsync(jobCtr, 0, 16, stream);
    hist_kernel<<<6250, 256, 0, stream>>>(tgt, et, invcnt, cur);
    scan_kernel<<<1, 256, 0, stream>>>(cur, offs);
    invcnt_kernel<<<6250, 256, 0, stream>>>(invcnt);
    scatter_edges<<<6250, 256, 0, stream>>>(src, tgt, et, invcnt, cur, eMeta);

    // layer l: x from emb (stride 128) or the previous layer's out slot (stride 512)
    const float* xin[3] = {emb, out + 256, out + 128};
    const int    xs[3]  = {128, 512, 512};
    const int    colOff[3] = {256, 128, 0};

    for (int lyr = 0; lyr < 3; ++lyr) {
        wprep_kernel<<<272, 256, 0, stream>>>(comp[lyr], basis[lyr], root[lyr], Wthi, Wtlo);
        layer_mfma<<<GRID_MFMA, 256, 0, stream>>>(xin[lyr], xs[lyr], Wthi, Wtlo, bias[lyr],
                                                  eMeta, offs, jobCtr + lyr, out, colOff[lyr]);
    }
    emb_copy<<<12500, 256, 0, stream>>>(emb, out);
}